// Round 28
// baseline (51.722 us; speedup 1.0000x reference)
//
#include <hip/hip_runtime.h>
#include <hip/hip_fp16.h>
#include <cstddef>

#define DIM 2048
#define NTOK 8192
#define NEUMANN_ITERS 6

// Math (validated rounds 1-27):
//   omega = P Q^T, P=[U|V], Q=[sV|-sU], G = Q^T P  (16x16)
//   Y = (I - G/2)^{-1}(I + G/2)  via Neumann-Horner: Y <- B + 0.5*G*Y, B=I+G/2
//   out = x + c . W^T,  c[r][k] = 0.5*s* sum_j Z[k][j] b[r][j],  Z = I + Y,
//     b[j<8] = av[j], b[j>=8] = -au[j-8];  a = [x.U | x.V] = x.W
//   G[r][c] = r<8 ? +s*WtW[8+r][c] : -s*WtW[r-8][c]  (in-kernel gram)
//
// r28 change: INDEPENDENT-BLOCK parallelism. All MFMA variants were pinned
// at 2 blocks/CU (16 rows/block => grid 512). r26 validated the no-LDS-W
// datapath (9.7KB LDS, VGPR 48, absmax 0.0156) but kept grid 512 — no
// occupancy gain. THIS round: 8 rows/block => grid 1024 => 4 independent
// blocks/CU (16 uncoupled waves/CU) + halved per-block serial chain.
// A-fragment rows 8-15 zeroed (MFMA half-idle — at 2.5% util, free);
// phase-1 x loads and phase-2 mem ops predicated rA<8 (also OOB guard).
// W gathers from L2 (256KB resident, ~256MB aggregate ~ 7us, overlapped).
// Merged gram+phase1 (r27, -1 pass). Swapped-operand phase 2 (r25).

typedef _Float16 h4 __attribute__((ext_vector_type(4)));
typedef float f32x4 __attribute__((ext_vector_type(4)));

__device__ __forceinline__ unsigned pkh(float lo, float hi) {
  auto p = __builtin_amdgcn_cvt_pkrtz(lo, hi);   // v_cvt_pkrtz_f16_f32
  return __builtin_bit_cast(unsigned, p);
}

// ---------------------------------------------------------------------------
// Fused MFMA kernel, no staged W. 256 thr = 4 waves; 8 rows/block;
// grid 1024 -> 4 blocks/CU. No workspace.
// ---------------------------------------------------------------------------
__global__ __launch_bounds__(256) void rora_fused(
    const float* __restrict__ x, const float* __restrict__ U,
    const float* __restrict__ V, const float* __restrict__ gate,
    float* __restrict__ out) {
  __shared__ float Gs[16][17];        // 1,088 B
  __shared__ float Ya[16][17];        // 1,088 B
  __shared__ float Yb[16][17];        // 1,088 B
  __shared__ float Wtw[16][17];       // 1,088 B
  __shared__ float As[16][17];        // 1,088 B
  __shared__ float Ared[4][64][4];    // 4,096 B
  __shared__ float Agred[4][64][4];   // 4,096 B   (total ~13.6 KB)
  const int t = threadIdx.x;
  const int lane = t & 63, wv = t >> 6;
  const int rA = lane & 15, g = lane >> 4;

  // W-column gather source for this thread's B-fragment column (k = rA)
  const float* Wcol = ((rA < 8) ? U : V) + (rA & 7);   // W[d][rA] = Wcol[8*d]

  // ---- MERGED phase 1 + gram: wave wv covers K-slice [wv*512,+512) ----
  const int row0 = blockIdx.x * 8;
  {
    f32x4 acca = {0.f, 0.f, 0.f, 0.f};
    f32x4 accg = {0.f, 0.f, 0.f, 0.f};
    const float* xrow = x + (size_t)(row0 + rA) * DIM;
    const bool live = (rA < 8);
#pragma unroll 4
    for (int step = 0; step < 32; ++step) {
      const int d0 = wv * 512 + step * 16 + g * 4;
      float4 xv = make_float4(0.f, 0.f, 0.f, 0.f);
      if (live) xv = *(const float4*)(xrow + d0);     // exec-masked load
      uint2 au = {pkh(xv.x, xv.y), pkh(xv.z, xv.w)};
      const h4 af = __builtin_bit_cast(h4, au);
      const float w0 = Wcol[8 * (d0 + 0)], w1 = Wcol[8 * (d0 + 1)];
      const float w2 = Wcol[8 * (d0 + 2)], w3 = Wcol[8 * (d0 + 3)];
      uint2 bu = {pkh(w0, w1), pkh(w2, w3)};
      const h4 bf = __builtin_bit_cast(h4, bu);
      acca = __builtin_amdgcn_mfma_f32_16x16x16f16(af, bf, acca, 0, 0, 0);
      accg = __builtin_amdgcn_mfma_f32_16x16x16f16(bf, bf, accg, 0, 0, 0);
    }
    Ared[wv][lane][0] = acca[0];
    Ared[wv][lane][1] = acca[1];
    Ared[wv][lane][2] = acca[2];
    Ared[wv][lane][3] = acca[3];
    Agred[wv][lane][0] = accg[0];
    Agred[wv][lane][1] = accg[1];
    Agred[wv][lane][2] = accg[2];
    Agred[wv][lane][3] = accg[3];
  }
  __syncthreads();
  {
    const int l = t & 63, j = t >> 6;
    const float sa = (Ared[0][l][j] + Ared[1][l][j]) +
                     (Ared[2][l][j] + Ared[3][l][j]);
    const float sgm = (Agred[0][l][j] + Agred[1][l][j]) +
                      (Agred[2][l][j] + Agred[3][l][j]);
    const int dr = (l >> 4) * 4 + j, dc = l & 15;   // D layout per m89
    As[dr][dc] = sa;     // a[row][k]
    Wtw[dr][dc] = sgm;   // WtW[i][jcol]
  }
  __syncthreads();

  // ---- G + Neumann setup ----
  const float sg = 1.f / (1.f + expf(-gate[0]));
  {
    const int r = t >> 4, c = t & 15;
    const float gv = (r < 8) ? sg * Wtw[r + 8][c] : -sg * Wtw[r - 8][c];
    Gs[r][c] = gv;
    Ya[r][c] = ((r == c) ? 1.f : 0.f) + 0.5f * gv;   // B = I + 0.5G
  }
  __syncthreads();
#pragma unroll
  for (int m = 0; m < NEUMANN_ITERS; ++m) {   // ends in Ya (last m odd)
    const int r = t >> 4, c = t & 15;
    const float (*Yp)[17] = (m & 1) ? Yb : Ya;
    float (*Yn)[17] = (m & 1) ? Ya : Yb;
    float acc = ((r == c) ? 1.f : 0.f) + 0.5f * Gs[r][c];
#pragma unroll
    for (int j = 0; j < 16; ++j)
      acc = fmaf(0.5f * Gs[r][j], Yp[j][c], acc);
    Yn[r][c] = acc;
    __syncthreads();
  }

  // ---- c fragment (lane holds c[r=rA][g*4+j]; serves as B-operand) ----
  h4 cf;
  {
    const float hs = 0.5f * sg;
    const int r = rA;
    float cj[4];
#pragma unroll
    for (int j = 0; j < 4; ++j) {
      const int k = g * 4 + j;
      float s = 0.f;
#pragma unroll
      for (int jj = 0; jj < 8; ++jj) {
        const float zA = Ya[k][jj] + ((k == jj) ? 1.f : 0.f);
        const float zB = Ya[k][8 + jj] + ((k == 8 + jj) ? 1.f : 0.f);
        s = fmaf(zA, As[r][8 + jj], s);    //  Z[k][j']   * av[j']
        s = fmaf(-zB, As[r][jj], s);       // -Z[k][8+j'] * au[j']
      }
      cj[j] = hs * s;
    }
    uint2 cu = {pkh(cj[0], cj[1]), pkh(cj[2], cj[3])};
    cf = __builtin_bit_cast(h4, cu);
  }

  // ---- phase 2: out = x + W.c^T via MFMA (swapped operands, r25) ----
  // D[d][r]: lane holds corr[row0+rA][dcol0+g*4+j] = one float4.
  {
    const float4* WB4 = (const float4*)((g < 2) ? U : V);
    const int gsel = g & 1;
    const bool live = (rA < 8);
    const float4* x4row = (const float4*)(x + (size_t)(row0 + rA) * DIM);
    float4* o4row = (float4*)(out + (size_t)(row0 + rA) * DIM);
    for (int nt = wv * 32; nt < wv * 32 + 32; ++nt) {
      const int dcol0 = nt * 16;
      const float4 wf4 = WB4[(dcol0 + rA) * 2 + gsel];
      uint2 bu = {pkh(wf4.x, wf4.y), pkh(wf4.z, wf4.w)};
      const h4 bf = __builtin_bit_cast(h4, bu);    // W[dcol0+rA][g*4+j]
      f32x4 z4 = {0.f, 0.f, 0.f, 0.f};
      const f32x4 o = __builtin_amdgcn_mfma_f32_16x16x16f16(bf, cf, z4, 0, 0, 0);
      if (live) {
        const int q4 = (dcol0 >> 2) + g;           // float4 index in row
        const float4 xv = x4row[q4];
        float4 ov;
        ov.x = xv.x + o[0];
        ov.y = xv.y + o[1];
        ov.z = xv.z + o[2];
        ov.w = xv.w + o[3];
        o4row[q4] = ov;
      }
    }
  }
}

extern "C" void kernel_launch(void* const* d_in, const int* in_sizes, int n_in,
                              void* d_out, int out_size, void* d_ws, size_t ws_size,
                              hipStream_t stream) {
  const float* x    = (const float*)d_in[0];
  const float* U    = (const float*)d_in[1];
  const float* V    = (const float*)d_in[2];
  const float* gate = (const float*)d_in[3];
  float* out = (float*)d_out;

  rora_fused<<<NTOK / 8, 256, 0, stream>>>(x, U, V, gate, out);
}

// Round 29
// 41.638 us; speedup vs baseline: 1.2422x; 1.2422x over previous
//
#include <hip/hip_runtime.h>
#include <hip/hip_fp16.h>
#include <cstddef>

#define DIM 2048
#define NTOK 8192
#define NEUMANN_ITERS 6
#define PLANE (DIM / 2 + 1)   // +1 uint4 pad: planes 4 banks apart (r22 fix)

// Math (validated rounds 1-28):
//   omega = P Q^T, P=[U|V], Q=[sV|-sU], G = Q^T P  (16x16)
//   Y = (I - G/2)^{-1}(I + G/2)  via Neumann-Horner: Y <- B + 0.5*G*Y, B=I+G/2
//   out = x + c . W^T,  c[r][k] = 0.5*s* sum_j Z[k][j] b[r][j],  Z = I + Y
//   G[r][c] = r<8 ? +s*WtW[8+r][c] : -s*WtW[r-8][c]  (in-kernel gram, r24)
//
// r29 change (on r27 champion, 40.6us): SOFTWARE-PIPELINED 2-TILE BLOCK.
// All blocks launch in lockstep -> phase-1 (pure read) and phase-2 (pure
// write) align chip-wide; each HBM direction runs at <=50% duty -> the 2x
// gap over the 21us floor. Persistent block owns TWO 16-row tiles:
//   ph1(t0)+gram -> setup/c0 -> {ph2(t0) || ph1(t1)} x16 -> c1 -> ph2(t1)
// The overlapped middle interleaves reads+writes per wave. Grid 256 x
// 512thr (8 waves: ph1 K-split 8x256, ph2 16 n-tiles/wave). Gram once.
// Fragment contracts byte-identical to r27 (A row=l&15, B col=l&15,
// k=(l>>4)*4+j; swapped-operand phase 2, r25).

typedef _Float16 h4 __attribute__((ext_vector_type(4)));
typedef float f32x4 __attribute__((ext_vector_type(4)));

__device__ __forceinline__ unsigned pkh(float lo, float hi) {
  auto p = __builtin_amdgcn_cvt_pkrtz(lo, hi);   // v_cvt_pkrtz_f16_f32
  return __builtin_bit_cast(unsigned, p);
}

__global__ __launch_bounds__(512) void rora_fused(
    const float* __restrict__ x, const float* __restrict__ U,
    const float* __restrict__ V, const float* __restrict__ gate,
    float* __restrict__ out) {
  __shared__ uint4 uvQ[4][PLANE];     // 65,600 B
  __shared__ float Gs[16][17];
  __shared__ float Ya[16][17];
  __shared__ float Yb[16][17];
  __shared__ float Wtw[16][17];
  __shared__ float As[16][17];
  __shared__ float Ared[8][64][4];    // 8,192 B
  __shared__ float Agred[8][64][4];   // 8,192 B  (total ~87.4 KB, 1 blk/CU)
  const int t = threadIdx.x;          // 0..511
  const int lane = t & 63, wv = t >> 6;   // wv 0..7
  const int rA = lane & 15, g = lane >> 4;
  const int row0 = blockIdx.x * 32;       // tile0: rows row0..+15, tile1: +16

  // ---- stage U,V -> LDS as f16 d-pairs (2 pairs per thread) ----
  {
    const float4* U4 = (const float4*)U;
    const float4* V4 = (const float4*)V;
#pragma unroll
    for (int rep = 0; rep < 2; ++rep) {
      const int P = rep * 512 + t;    // d-pair (2P, 2P+1); covers 0..1023
      const float4 a0 = U4[4 * P + 0], a1 = U4[4 * P + 1];
      const float4 a2 = U4[4 * P + 2], a3 = U4[4 * P + 3];
      const float4 b0 = V4[4 * P + 0], b1 = V4[4 * P + 1];
      const float4 b2 = V4[4 * P + 2], b3 = V4[4 * P + 3];
      uvQ[0][P] = make_uint4(pkh(a0.x, a2.x), pkh(a0.y, a2.y),
                             pkh(a0.z, a2.z), pkh(a0.w, a2.w));
      uvQ[1][P] = make_uint4(pkh(a1.x, a3.x), pkh(a1.y, a3.y),
                             pkh(a1.z, a3.z), pkh(a1.w, a3.w));
      uvQ[2][P] = make_uint4(pkh(b0.x, b2.x), pkh(b0.y, b2.y),
                             pkh(b0.z, b2.z), pkh(b0.w, b2.w));
      uvQ[3][P] = make_uint4(pkh(b1.x, b3.x), pkh(b1.y, b3.y),
                             pkh(b1.z, b3.z), pkh(b1.w, b3.w));
    }
  }
  __syncthreads();

  const int q1 = rA >> 2, c1 = rA & 3;   // B column k = rA
  const unsigned* uvW = (const unsigned*)&uvQ[q1][0];

  // ---- merged gram + ph1(tile0): wave wv covers K [wv*256,+256) ----
  {
    f32x4 acca = {0.f, 0.f, 0.f, 0.f};
    f32x4 accg = {0.f, 0.f, 0.f, 0.f};
    const float* xrow = x + (size_t)(row0 + rA) * DIM;
#pragma unroll 4
    for (int step = 0; step < 16; ++step) {
      const int d0 = wv * 256 + step * 16 + g * 4;
      const float4 xv = *(const float4*)(xrow + d0);
      uint2 au = {pkh(xv.x, xv.y), pkh(xv.z, xv.w)};
      const h4 af = __builtin_bit_cast(h4, au);
      const int P0 = d0 >> 1;
      uint2 bu = {uvW[P0 * 4 + c1], uvW[(P0 + 1) * 4 + c1]};
      const h4 bf = __builtin_bit_cast(h4, bu);
      acca = __builtin_amdgcn_mfma_f32_16x16x16f16(af, bf, acca, 0, 0, 0);
      accg = __builtin_amdgcn_mfma_f32_16x16x16f16(bf, bf, accg, 0, 0, 0);
    }
#pragma unroll
    for (int j = 0; j < 4; ++j) {
      Ared[wv][lane][j] = acca[j];
      Agred[wv][lane][j] = accg[j];
    }
  }
  __syncthreads();
  if (t < 256) {
    const int l = t & 63, j = t >> 6;
    float sa = 0.f, sgm = 0.f;
#pragma unroll
    for (int w = 0; w < 8; ++w) { sa += Ared[w][l][j]; sgm += Agred[w][l][j]; }
    const int dr = (l >> 4) * 4 + j, dc = l & 15;   // D layout per m89
    As[dr][dc] = sa;
    Wtw[dr][dc] = sgm;
  }
  __syncthreads();

  // ---- G + Neumann setup ----
  const float sg = 1.f / (1.f + expf(-gate[0]));
  if (t < 256) {
    const int r = t >> 4, c = t & 15;
    const float gv = (r < 8) ? sg * Wtw[r + 8][c] : -sg * Wtw[r - 8][c];
    Gs[r][c] = gv;
    Ya[r][c] = ((r == c) ? 1.f : 0.f) + 0.5f * gv;   // B = I + 0.5G
  }
  __syncthreads();
#pragma unroll
  for (int m = 0; m < NEUMANN_ITERS; ++m) {   // ends in Ya (last m odd)
    if (t < 256) {
      const int r = t >> 4, c = t & 15;
      const float (*Yp)[17] = (m & 1) ? Yb : Ya;
      float (*Yn)[17] = (m & 1) ? Ya : Yb;
      float acc = ((r == c) ? 1.f : 0.f) + 0.5f * Gs[r][c];
#pragma unroll
      for (int j = 0; j < 16; ++j)
        acc = fmaf(0.5f * Gs[r][j], Yp[j][c], acc);
      Yn[r][c] = acc;
    }
    __syncthreads();
  }

  const float hs = 0.5f * sg;
  // ---- c0 fragment (lane holds c[r=rA][g*4+j]) ----
  h4 cf0;
  {
    float cj[4];
#pragma unroll
    for (int j = 0; j < 4; ++j) {
      const int k = g * 4 + j;
      float s = 0.f;
#pragma unroll
      for (int jj = 0; jj < 8; ++jj) {
        const float zA = Ya[k][jj] + ((k == jj) ? 1.f : 0.f);
        const float zB = Ya[k][8 + jj] + ((k == 8 + jj) ? 1.f : 0.f);
        s = fmaf(zA, As[rA][8 + jj], s);
        s = fmaf(-zB, As[rA][jj], s);
      }
      cj[j] = hs * s;
    }
    uint2 cu = {pkh(cj[0], cj[1]), pkh(cj[2], cj[3])};
    cf0 = __builtin_bit_cast(h4, cu);
  }

  // ---- OVERLAPPED: ph2(tile0) stores || ph1(tile1) loads, 16 iters ----
  f32x4 acca1 = {0.f, 0.f, 0.f, 0.f};
  {
    const float* xrow1 = x + (size_t)(row0 + 16 + rA) * DIM;
    const float4* x4row0 = (const float4*)(x + (size_t)(row0 + rA) * DIM);
    float4* o4row0 = (float4*)(out + (size_t)(row0 + rA) * DIM);
    const int par = rA & 1;
#pragma unroll 2
    for (int i = 0; i < 16; ++i) {
      // ph1(tile1), step i (issue loads early)
      const int d0 = wv * 256 + i * 16 + g * 4;
      const float4 xv = *(const float4*)(xrow1 + d0);
      // ph2(tile0), nt = wv*16 + i
      const int dcol0 = (wv * 16 + i) * 16;
      const uint4 wq = uvQ[g][(dcol0 + rA) >> 1];  // plane q = k>>2 = g
      const unsigned w01 = par ? ((wq.x >> 16) | (wq.y & 0xffff0000u))
                               : ((wq.x & 0xffffu) | (wq.y << 16));
      const unsigned w23 = par ? ((wq.z >> 16) | (wq.w & 0xffff0000u))
                               : ((wq.z & 0xffffu) | (wq.w << 16));
      uint2 b2u = {w01, w23};
      const h4 bf2 = __builtin_bit_cast(h4, b2u);  // W[dcol0+rA][g*4+j]
      f32x4 z4 = {0.f, 0.f, 0.f, 0.f};
      const f32x4 o = __builtin_amdgcn_mfma_f32_16x16x16f16(bf2, cf0, z4, 0, 0, 0);
      const int q4 = (dcol0 >> 2) + g;
      const float4 xv0 = x4row0[q4];
      float4 ov;
      ov.x = xv0.x + o[0];
      ov.y = xv0.y + o[1];
      ov.z = xv0.z + o[2];
      ov.w = xv0.w + o[3];
      o4row0[q4] = ov;
      // ph1(tile1) compute
      uint2 au = {pkh(xv.x, xv.y), pkh(xv.z, xv.w)};
      const h4 af = __builtin_bit_cast(h4, au);
      const int P0 = d0 >> 1;
      uint2 bu = {uvW[P0 * 4 + c1], uvW[(P0 + 1) * 4 + c1]};
      const h4 bf = __builtin_bit_cast(h4, bu);
      acca1 = __builtin_amdgcn_mfma_f32_16x16x16f16(af, bf, acca1, 0, 0, 0);
    }
  }
#pragma unroll
  for (int j = 0; j < 4; ++j) Ared[wv][lane][j] = acca1[j];
  __syncthreads();
  if (t < 256) {
    const int l = t & 63, j = t >> 6;
    float sa = 0.f;
#pragma unroll
    for (int w = 0; w < 8; ++w) sa += Ared[w][l][j];
    As[(l >> 4) * 4 + j][l & 15] = sa;
  }
  __syncthreads();

  // ---- c1 fragment ----
  h4 cf1;
  {
    float cj[4];
#pragma unroll
    for (int j = 0; j < 4; ++j) {
      const int k = g * 4 + j;
      float s = 0.f;
#pragma unroll
      for (int jj = 0; jj < 8; ++jj) {
        const float zA = Ya[k][jj] + ((k == jj) ? 1.f : 0.f);
        const float zB = Ya[k][8 + jj] + ((k == 8 + jj) ? 1.f : 0.f);
        s = fmaf(zA, As[rA][8 + jj], s);
        s = fmaf(-zB, As[rA][jj], s);
      }
      cj[j] = hs * s;
    }
    uint2 cu = {pkh(cj[0], cj[1]), pkh(cj[2], cj[3])};
    cf1 = __builtin_bit_cast(h4, cu);
  }

  // ---- ph2(tile1): 16 n-tiles per wave ----
  {
    const int par = rA & 1;
    const float4* x4row1 = (const float4*)(x + (size_t)(row0 + 16 + rA) * DIM);
    float4* o4row1 = (float4*)(out + (size_t)(row0 + 16 + rA) * DIM);
    for (int i = 0; i < 16; ++i) {
      const int dcol0 = (wv * 16 + i) * 16;
      const uint4 wq = uvQ[g][(dcol0 + rA) >> 1];
      const unsigned w01 = par ? ((wq.x >> 16) | (wq.y & 0xffff0000u))
                               : ((wq.x & 0xffffu) | (wq.y << 16));
      const unsigned w23 = par ? ((wq.z >> 16) | (wq.w & 0xffff0000u))
                               : ((wq.z & 0xffffu) | (wq.w << 16));
      uint2 bu = {w01, w23};
      const h4 bf = __builtin_bit_cast(h4, bu);
      f32x4 z4 = {0.f, 0.f, 0.f, 0.f};
      const f32x4 o = __builtin_amdgcn_mfma_f32_16x16x16f16(bf, cf1, z4, 0, 0, 0);
      const int q4 = (dcol0 >> 2) + g;
      const float4 xv = x4row1[q4];
      float4 ov;
      ov.x = xv.x + o[0];
      ov.y = xv.y + o[1];
      ov.z = xv.z + o[2];
      ov.w = xv.w + o[3];
      o4row1[q4] = ov;
    }
  }
}

extern "C" void kernel_launch(void* const* d_in, const int* in_sizes, int n_in,
                              void* d_out, int out_size, void* d_ws, size_t ws_size,
                              hipStream_t stream) {
  const float* x    = (const float*)d_in[0];
  const float* U    = (const float*)d_in[1];
  const float* V    = (const float*)d_in[2];
  const float* gate = (const float*)d_in[3];
  float* out = (float*)d_out;

  rora_fused<<<NTOK / 32, 512, 0, stream>>>(x, U, V, gate, out);
}

// Round 30
// 40.530 us; speedup vs baseline: 1.2761x; 1.0273x over previous
//
#include <hip/hip_runtime.h>
#include <hip/hip_fp16.h>
#include <cstddef>

#define DIM 2048
#define NTOK 8192
#define NEUMANN_ITERS 6
#define PLANE (DIM / 2 + 1)   // +1 uint4 pad: planes 4 banks apart (r22 fix)

// FINAL (r27 champion, 40.6us total, absmax 0.0156). Validated r1-r29.
// Math:
//   omega = P Q^T, P=[U|V], Q=[sV|-sU], G = Q^T P  (16x16)
//   Y = (I - G/2)^{-1}(I + G/2)  via Neumann-Horner: Y <- B + 0.5*G*Y, B=I+G/2
//   out = x + c . W^T,  c[r][k] = 0.5*s* sum_j Z[k][j] b[r][j],  Z = I + Y,
//     b[j<8] = av[j], b[j>=8] = -au[j-8];  a = [x.U | x.V] = x.W
//   G[r][c] = r<8 ? +s*WtW[8+r][c] : -s*WtW[r-8][c]  (in-kernel gram, r24)
//
// Structure: single kernel, 256 thr = 4 waves, 16 rows/block, grid 512.
//   - U,V staged once in LDS as f16 d-pairs (uvQ, bank-padded planes).
//   - MERGED phase1+gram (r27): a = x.W and WtW = W^T W share the
//     B-fragment gather; gram MFMAs ride the idle matrix pipe.
//   - 16x16 Neumann-Horner in LDS (6 iters, f32).
//   - Phase 2 swapped-operand MFMA (r25): D lane-holds one float4 of a
//     row -> float4 I/O epilogue.
//   - MFMA 16x16x16f16 contracts: A row=l&15, B col=l&15, k=(l>>4)*4+j,
//     D col=l&15 row=(l>>4)*4+reg (m89).
// Session lessons: occupancy 8->32 waves/CU no effect (r16/r23/r28);
// x-in-regs spills (r13/r17/r19); fp8 decode 2x VALU (r15); 1024-thr
// blocks cap VGPR at 64 (r19); read/write-phase overlap negative (r29).

typedef _Float16 h4 __attribute__((ext_vector_type(4)));
typedef float f32x4 __attribute__((ext_vector_type(4)));

__device__ __forceinline__ unsigned pkh(float lo, float hi) {
  auto p = __builtin_amdgcn_cvt_pkrtz(lo, hi);   // v_cvt_pkrtz_f16_f32
  return __builtin_bit_cast(unsigned, p);
}

__global__ __launch_bounds__(256) void rora_fused(
    const float* __restrict__ x, const float* __restrict__ U,
    const float* __restrict__ V, const float* __restrict__ gate,
    float* __restrict__ out) {
  __shared__ uint4 uvQ[4][PLANE];     // 65,600 B
  __shared__ float Gs[16][17];
  __shared__ float Ya[16][17];
  __shared__ float Yb[16][17];
  __shared__ float Wtw[16][17];
  __shared__ float As[16][17];
  __shared__ float Ared[4][64][4];
  __shared__ float Agred[4][64][4];   // total ~79.2 KB, 2 blocks/CU
  const int t = threadIdx.x;
  const int lane = t & 63, wv = t >> 6;
  const int rA = lane & 15, g = lane >> 4;

  // ---- stage U,V -> LDS as f16 d-pairs (4 pairs per thread) ----
  {
    const float4* U4 = (const float4*)U;
    const float4* V4 = (const float4*)V;
#pragma unroll
    for (int rep = 0; rep < 4; ++rep) {
      const int P = rep * 256 + t;    // d-pair (2P, 2P+1)
      const float4 a0 = U4[4 * P + 0], a1 = U4[4 * P + 1];
      const float4 a2 = U4[4 * P + 2], a3 = U4[4 * P + 3];
      const float4 b0 = V4[4 * P + 0], b1 = V4[4 * P + 1];
      const float4 b2 = V4[4 * P + 2], b3 = V4[4 * P + 3];
      uvQ[0][P] = make_uint4(pkh(a0.x, a2.x), pkh(a0.y, a2.y),
                             pkh(a0.z, a2.z), pkh(a0.w, a2.w));
      uvQ[1][P] = make_uint4(pkh(a1.x, a3.x), pkh(a1.y, a3.y),
                             pkh(a1.z, a3.z), pkh(a1.w, a3.w));
      uvQ[2][P] = make_uint4(pkh(b0.x, b2.x), pkh(b0.y, b2.y),
                             pkh(b0.z, b2.z), pkh(b0.w, b2.w));
      uvQ[3][P] = make_uint4(pkh(b1.x, b3.x), pkh(b1.y, b3.y),
                             pkh(b1.z, b3.z), pkh(b1.w, b3.w));
    }
  }
  __syncthreads();   // staging visible before MFMA reads

  // ---- MERGED phase 1 + gram: wave wv covers K-slice [wv*512,+512) ----
  const int row0 = blockIdx.x * 16;
  {
    f32x4 acca = {0.f, 0.f, 0.f, 0.f};
    f32x4 accg = {0.f, 0.f, 0.f, 0.f};
    const float* xrow = x + (size_t)(row0 + rA) * DIM;
    const int q1 = rA >> 2, c1 = rA & 3;   // B column k = rA
    const unsigned* uvW = (const unsigned*)&uvQ[q1][0];
#pragma unroll 4
    for (int step = 0; step < 32; ++step) {
      const int d0 = wv * 512 + step * 16 + g * 4;
      const float4 xv = *(const float4*)(xrow + d0);
      uint2 au = {pkh(xv.x, xv.y), pkh(xv.z, xv.w)};
      const h4 af = __builtin_bit_cast(h4, au);
      const int P0 = d0 >> 1;
      uint2 bu = {uvW[P0 * 4 + c1], uvW[(P0 + 1) * 4 + c1]};
      const h4 bf = __builtin_bit_cast(h4, bu);
      acca = __builtin_amdgcn_mfma_f32_16x16x16f16(af, bf, acca, 0, 0, 0);
      accg = __builtin_amdgcn_mfma_f32_16x16x16f16(bf, bf, accg, 0, 0, 0);
    }
    Ared[wv][lane][0] = acca[0];
    Ared[wv][lane][1] = acca[1];
    Ared[wv][lane][2] = acca[2];
    Ared[wv][lane][3] = acca[3];
    Agred[wv][lane][0] = accg[0];
    Agred[wv][lane][1] = accg[1];
    Agred[wv][lane][2] = accg[2];
    Agred[wv][lane][3] = accg[3];
  }
  __syncthreads();
  {
    const int l = t & 63, j = t >> 6;
    const float sa = (Ared[0][l][j] + Ared[1][l][j]) +
                     (Ared[2][l][j] + Ared[3][l][j]);
    const float sgm = (Agred[0][l][j] + Agred[1][l][j]) +
                      (Agred[2][l][j] + Agred[3][l][j]);
    const int dr = (l >> 4) * 4 + j, dc = l & 15;   // D layout per m89
    As[dr][dc] = sa;     // a[row][k]
    Wtw[dr][dc] = sgm;   // WtW[i][jcol]
  }
  __syncthreads();

  // ---- G + Neumann setup ----
  const float sg = 1.f / (1.f + expf(-gate[0]));
  {
    const int r = t >> 4, c = t & 15;
    const float gv = (r < 8) ? sg * Wtw[r + 8][c] : -sg * Wtw[r - 8][c];
    Gs[r][c] = gv;
    Ya[r][c] = ((r == c) ? 1.f : 0.f) + 0.5f * gv;   // B = I + 0.5G
  }
  __syncthreads();
#pragma unroll
  for (int m = 0; m < NEUMANN_ITERS; ++m) {   // ends in Ya (last m odd)
    const int r = t >> 4, c = t & 15;
    const float (*Yp)[17] = (m & 1) ? Yb : Ya;
    float (*Yn)[17] = (m & 1) ? Ya : Yb;
    float acc = ((r == c) ? 1.f : 0.f) + 0.5f * Gs[r][c];
#pragma unroll
    for (int j = 0; j < 16; ++j)
      acc = fmaf(0.5f * Gs[r][j], Yp[j][c], acc);
    Yn[r][c] = acc;
    __syncthreads();
  }

  // ---- c fragment (lane holds c[r=rA][g*4+j]; serves as B-operand) ----
  h4 cf;
  {
    const float hs = 0.5f * sg;
    const int r = rA;
    float cj[4];
#pragma unroll
    for (int j = 0; j < 4; ++j) {
      const int k = g * 4 + j;
      float s = 0.f;
#pragma unroll
      for (int jj = 0; jj < 8; ++jj) {
        const float zA = Ya[k][jj] + ((k == jj) ? 1.f : 0.f);
        const float zB = Ya[k][8 + jj] + ((k == 8 + jj) ? 1.f : 0.f);
        s = fmaf(zA, As[r][8 + jj], s);    //  Z[k][j']   * av[j']
        s = fmaf(-zB, As[r][jj], s);       // -Z[k][8+j'] * au[j']
      }
      cj[j] = hs * s;
    }
    uint2 cu = {pkh(cj[0], cj[1]), pkh(cj[2], cj[3])};
    cf = __builtin_bit_cast(h4, cu);
  }

  // ---- phase 2: out = x + W.c^T via MFMA (swapped operands, r25) ----
  // D[d][r]: lane holds corr[row0+rA][dcol0+g*4+j] = one float4.
  {
    const int par = rA & 1;
    const float4* x4row = (const float4*)(x + (size_t)(row0 + rA) * DIM);
    float4* o4row = (float4*)(out + (size_t)(row0 + rA) * DIM);
    for (int nt = wv * 32; nt < wv * 32 + 32; ++nt) {
      const int dcol0 = nt * 16;
      const uint4 wq = uvQ[g][(dcol0 + rA) >> 1];  // plane q = k>>2 = g
      const unsigned w01 = par ? ((wq.x >> 16) | (wq.y & 0xffff0000u))
                               : ((wq.x & 0xffffu) | (wq.y << 16));
      const unsigned w23 = par ? ((wq.z >> 16) | (wq.w & 0xffff0000u))
                               : ((wq.z & 0xffffu) | (wq.w << 16));
      uint2 bu = {w01, w23};
      const h4 bf = __builtin_bit_cast(h4, bu);    // W[dcol0+rA][g*4+j]
      f32x4 z4 = {0.f, 0.f, 0.f, 0.f};
      const f32x4 o = __builtin_amdgcn_mfma_f32_16x16x16f16(bf, cf, z4, 0, 0, 0);
      const int q4 = (dcol0 >> 2) + g;             // float4 index in row
      const float4 xv = x4row[q4];
      float4 ov;
      ov.x = xv.x + o[0];
      ov.y = xv.y + o[1];
      ov.z = xv.z + o[2];
      ov.w = xv.w + o[3];
      o4row[q4] = ov;
    }
  }
}

extern "C" void kernel_launch(void* const* d_in, const int* in_sizes, int n_in,
                              void* d_out, int out_size, void* d_ws, size_t ws_size,
                              hipStream_t stream) {
  const float* x    = (const float*)d_in[0];
  const float* U    = (const float*)d_in[1];
  const float* V    = (const float*)d_in[2];
  const float* gate = (const float*)d_in[3];
  float* out = (float*)d_out;

  rora_fused<<<NTOK / 16, 256, 0, stream>>>(x, U, V, gate, out);
}